// Round 1
// 226.227 us; speedup vs baseline: 1.0566x; 1.0566x over previous
//
#include <hip/hip_runtime.h>
#include <hip/hip_bf16.h>

// ---------- types ----------
typedef float f32x4 __attribute__((ext_vector_type(4)));
typedef int   v8i   __attribute__((ext_vector_type(8)));
typedef __attribute__((address_space(3))) unsigned int       lds_uint;
typedef __attribute__((address_space(1))) const unsigned int glb_uint;

// ---------- helpers ----------
__device__ __forceinline__ float tanh_fast(float x) {
    float e = __expf(-2.0f * fabsf(x));
    float r = (1.0f - e) / (1.0f + e);
    return copysignf(r, x);
}
__device__ __forceinline__ unsigned char f2fp8(float v) {
    return (unsigned char)(__builtin_amdgcn_cvt_pk_fp8_f32(v, 0.0f, 0, false) & 0xff);
}
__device__ __forceinline__ unsigned short f2h(float v) {
    _Float16 h = (_Float16)v;
    unsigned short u;
    __builtin_memcpy(&u, &h, 2);
    return u;
}
__device__ __forceinline__ float h2f(unsigned short u) {
    _Float16 h;
    __builtin_memcpy(&h, &u, 2);
    return (float)h;
}

// ---------- prep: x->fp8; proj W ->fp8(x16) T; r1/r2 ->fp8(x16) T; bias concat ----------
__global__ __launch_bounds__(256) void prep(
    const float* __restrict__ x,
    const float* __restrict__ theta_w, const float* __restrict__ phi_w,
    const float* __restrict__ psi_w,   const float* __restrict__ r1_w,
    const float* __restrict__ r2_w,
    const float* __restrict__ theta_b, const float* __restrict__ phi_b,
    const float* __restrict__ psi_b,
    unsigned char* __restrict__ xb8, unsigned char* __restrict__ wCat8T,
    unsigned char* __restrict__ r1T8, unsigned char* __restrict__ r2T8,
    float* __restrict__ bCat) {
    const int b = blockIdx.x, t = threadIdx.x;
    if (b < 8192) {                       // cast x -> fp8
        long i = ((long)b * 256 + t) * 4;
        float4 f = *(const float4*)(x + i);
        int w = __builtin_amdgcn_cvt_pk_fp8_f32(f.x, f.y, 0, false);
        w = __builtin_amdgcn_cvt_pk_fp8_f32(f.z, f.w, w, true);
        *(unsigned int*)(xb8 + i) = (unsigned int)w;
    } else if (b < 11264) {               // proj weights (512x512 each), x16, transposed
        const int sel = (b - 8192) >> 10;
        const int idx = ((b - 8192) & 1023) * 256 + t;
        const float* w = sel == 0 ? theta_w : (sel == 1 ? phi_w : psi_w);
        const int r = idx >> 9, c = idx & 511;
        wCat8T[(long)(sel * 512 + c) * 512 + r] = f2fp8(w[idx] * 16.0f);
    } else if (b < 11776) {               // r1 (512x256) -> fp8 x16 T
        const int idx = (b - 11264) * 256 + t;
        const int r = idx >> 8, c = idx & 255;
        r1T8[(long)c * 512 + r] = f2fp8(r1_w[idx] * 16.0f);
    } else if (b < 12288) {               // r2 (256x512) -> fp8 x16 T
        const int idx = (b - 11776) * 256 + t;
        const int r = idx >> 9, c = idx & 511;
        r2T8[(long)c * 256 + r] = f2fp8(r2_w[idx] * 16.0f);
    } else {                              // bias concat (1536)
        const int i = (b - 12288) * 256 + t;
        if (i < 1536)
            bCat[i] = i < 512 ? theta_b[i] : (i < 1024 ? phi_b[i - 512] : psi_b[i - 1024]);
    }
}

// ---------- row softmax: read fp16 S row, write fp8 P in-place (first half of row) ----------
__global__ __launch_bounds__(256) void softmax_fp8(unsigned short* __restrict__ S) {
    const size_t row = (size_t)blockIdx.y * 2048 + blockIdx.x;
    unsigned short* p = S + row * 2048;
    const int t = threadIdx.x;
    uint4 raw = *(uint4*)(p + t * 8);
    unsigned int w[4] = {raw.x, raw.y, raw.z, raw.w};
    float v[8];
#pragma unroll
    for (int i = 0; i < 4; ++i) {
        v[2 * i]     = h2f((unsigned short)(w[i] & 0xffffu));
        v[2 * i + 1] = h2f((unsigned short)(w[i] >> 16));
    }
    float mx = v[0];
#pragma unroll
    for (int i = 1; i < 8; ++i) mx = fmaxf(mx, v[i]);
#pragma unroll
    for (int off = 32; off > 0; off >>= 1) mx = fmaxf(mx, __shfl_xor(mx, off));
    __shared__ float red[8];
    const int wave = t >> 6, lane = t & 63;
    if (lane == 0) red[wave] = mx;
    __syncthreads();
    mx = fmaxf(fmaxf(red[0], red[1]), fmaxf(red[2], red[3]));
    float s = 0.0f;
#pragma unroll
    for (int i = 0; i < 8; ++i) { v[i] = __expf(v[i] - mx); s += v[i]; }
#pragma unroll
    for (int off = 32; off > 0; off >>= 1) s += __shfl_xor(s, off);
    if (lane == 0) red[4 + wave] = s;
    __syncthreads();
    s = red[4] + red[5] + red[6] + red[7];
    const float inv = 1.0f / s;
    int o0 = __builtin_amdgcn_cvt_pk_fp8_f32(v[0] * inv, v[1] * inv, 0, false);
    o0 = __builtin_amdgcn_cvt_pk_fp8_f32(v[2] * inv, v[3] * inv, o0, true);
    int o1 = __builtin_amdgcn_cvt_pk_fp8_f32(v[4] * inv, v[5] * inv, 0, false);
    o1 = __builtin_amdgcn_cvt_pk_fp8_f32(v[6] * inv, v[7] * inv, o1, true);
    uint2 ov; ov.x = (unsigned int)o0; ov.y = (unsigned int)o1;
    *(uint2*)((unsigned char*)p + t * 8) = ov;   // after barrier 2; reads were before barrier 1
}

// ---------- fp8 GEMM: 128x128 tile, BK=128, MX-scaled K=128 MFMA (unit scales) ----------
// C[m][n] = sum_k A[m][k]*Bt[n][k]; A/Bt fp8, row pitches ldaB/ldbB bytes.
// MODE 0 proj:  v=acc/16+bCat[col]; col<1024 -> fp8 TH8/PH8 (pitch 512);
//               col>=1024 -> V^T (dword stores: 4 l-consecutive rows packed)
// MODE 1 qkt:   fp16 -> outH, ldc elems
// MODE 2 pv:    fp8  -> out8, pitch 512
// MODE 3 r1:    v=acc/16+bias; leaky 0.2; fp8 -> out8, pitch 256
// MODE 4 r2:    v=acc/16+bias; tanh; +resid; fp32 -> outF, ldc 512
template <int MODE>
__global__ __launch_bounds__(256) void gemm_fp8(
    const unsigned char* __restrict__ A,
    const unsigned char* __restrict__ Bt,
    const float* __restrict__ bias,
    const float* __restrict__ resid,
    unsigned short* __restrict__ outH,
    unsigned char* __restrict__ out8,
    unsigned char* __restrict__ out8b,
    unsigned char* __restrict__ outV,
    float* __restrict__ outF,
    int K, int ldaB, int ldbB, int ldc, long sA, long sB, long sC) {
    __shared__ unsigned char As[128 * 128];
    __shared__ unsigned char Bs[128 * 128];

    const int tid  = threadIdx.x;
    const int lane = tid & 63, wave = tid >> 6;
    const int m16  = lane & 15, quad = lane >> 4;
    const int wm   = (wave >> 1) << 6, wn = (wave & 1) << 6;
    const int m0   = blockIdx.x << 7, n0 = blockIdx.y << 7;

    const int srow = lane >> 3;
    const int uswz = (lane & 7) ^ srow;

    const unsigned char* Abase = A  + (long)blockIdx.z * sA + (long)m0 * ldaB;
    const unsigned char* Bbase = Bt + (long)blockIdx.z * sB + (long)n0 * ldbB;
    const int stR = (wave << 5) + srow;
    const long gA0 = (long)stR * ldaB + (uswz << 4);
    const long gB0 = (long)stR * ldbB + (uswz << 4);

    // LDS read addressing: LDS 16B-unit u of row m holds global unit u^(m&7).
    // A lane's 32 global bytes (units 2q, 2q+1) live contiguously at 32B region
    // P = quad ^ ((m&7)>>1); half order flips with m&1. Two ds_read_b128 with a
    // conditional half-swap -> 16B column index has lane-varying bit0 ->
    // 8 lanes per 16B column across the wave = bank-conflict-optimal.
    const int s8  = m16 & 7;                        // == m&7 == n&7 for all frags
    const int P   = quad ^ (s8 >> 1);
    const int cLo = (P << 1) + (s8 & 1);            // 16B col of global unit 2q
    const int offLo = cLo << 4;
    const int offHi = (cLo ^ 1) << 4;               // 16B col of global unit 2q+1

    f32x4 acc[4][4] = {};

    union F8 { v8i v; int4 q[2]; };

    for (int k0 = 0; k0 < K; k0 += 128) {
        __syncthreads();
#pragma unroll
        for (int i = 0; i < 4; ++i) {
            const unsigned char* gp = Abase + gA0 + (long)(i << 3) * ldaB + k0;
            unsigned char* lp = &As[(((wave << 5) + (i << 3)) << 7)];
            __builtin_amdgcn_global_load_lds((glb_uint*)gp, (lds_uint*)lp, 16, 0, 0);
        }
#pragma unroll
        for (int i = 0; i < 4; ++i) {
            const unsigned char* gp = Bbase + gB0 + (long)(i << 3) * ldbB + k0;
            unsigned char* lp = &Bs[(((wave << 5) + (i << 3)) << 7)];
            __builtin_amdgcn_global_load_lds((glb_uint*)gp, (lds_uint*)lp, 16, 0, 0);
        }
        __syncthreads();
        // MX-scaled K=128 MFMA: lane holds A[m][k=quad*32 .. +31]
        F8 af[4], bg[4];
#pragma unroll
        for (int f = 0; f < 4; ++f) {
            const int m = wm + (f << 4) + m16;
            const int n = wn + (f << 4) + m16;
            af[f].q[0] = *(const int4*)&As[(m << 7) + offLo];
            af[f].q[1] = *(const int4*)&As[(m << 7) + offHi];
            bg[f].q[0] = *(const int4*)&Bs[(n << 7) + offLo];
            bg[f].q[1] = *(const int4*)&Bs[(n << 7) + offHi];
        }
#pragma unroll
        for (int fi = 0; fi < 4; ++fi)
#pragma unroll
            for (int fj = 0; fj < 4; ++fj)
                acc[fi][fj] = __builtin_amdgcn_mfma_scale_f32_16x16x128_f8f6f4(
                    af[fi].v, bg[fj].v, acc[fi][fj],
                    0, 0,            // cbsz=0 (A=e4m3), blgp=0 (B=e4m3)
                    0, 127,          // A scale: opsel 0, E8M0 127 = 1.0
                    0, 127);         // B scale: 1.0
    }

    const long zC = (long)blockIdx.z * sC;

    if (MODE == 0) {
        const int sel = n0 >> 9;                         // block-uniform
        if (sel < 2) {
            unsigned char* dst = sel == 0 ? out8 : out8b;
#pragma unroll
            for (int fj = 0; fj < 4; ++fj) {
                const int col = n0 + wn + (fj << 4) + m16;
                const int cb  = col & 511;
                const float bv = bias[col];
#pragma unroll
                for (int fi = 0; fi < 4; ++fi)
#pragma unroll
                    for (int r = 0; r < 4; ++r) {
                        const int row = m0 + wm + (fi << 4) + (quad << 2) + r;
                        dst[(long)row * 512 + cb] = f2fp8(acc[fi][fj][r] * 0.0625f + bv);
                    }
            }
        } else {                                         // V^T: pack 4 l-rows per dword
            const int z = m0 >> 11, l0 = (m0 & 2047) + wm + (quad << 2);
#pragma unroll
            for (int fj = 0; fj < 4; ++fj) {
                const int col = n0 + wn + (fj << 4) + m16;
                const int h   = col & 511;
                const float bv = bias[col];
#pragma unroll
                for (int fi = 0; fi < 4; ++fi) {
                    int w = __builtin_amdgcn_cvt_pk_fp8_f32(
                        acc[fi][fj][0] * 0.0625f + bv, acc[fi][fj][1] * 0.0625f + bv, 0, false);
                    w = __builtin_amdgcn_cvt_pk_fp8_f32(
                        acc[fi][fj][2] * 0.0625f + bv, acc[fi][fj][3] * 0.0625f + bv, w, true);
                    *(unsigned int*)(outV + ((long)z * 512 + h) * 2048 + l0 + (fi << 4)) =
                        (unsigned int)w;
                }
            }
        }
    } else {
#pragma unroll
        for (int fj = 0; fj < 4; ++fj) {
            const int col = n0 + wn + (fj << 4) + m16;
            float bv = 0.0f;
            if (MODE >= 3) bv = bias[col];
#pragma unroll
            for (int fi = 0; fi < 4; ++fi)
#pragma unroll
                for (int r = 0; r < 4; ++r) {
                    const int row = m0 + wm + (fi << 4) + (quad << 2) + r;
                    float v = acc[fi][fj][r];
                    if (MODE == 1) {
                        outH[zC + (long)row * ldc + col] = f2h(v);
                    } else if (MODE == 2) {
                        out8[zC + (long)row * 512 + col] = f2fp8(v);
                    } else if (MODE == 3) {
                        v = v * 0.0625f + bv;
                        v = v > 0.0f ? v : 0.2f * v;
                        out8[(long)row * 256 + col] = f2fp8(v);
                    } else {
                        v = v * 0.0625f + bv;
                        const long idx = (long)row * ldc + col;
                        outF[idx] = tanh_fast(v) + resid[idx];
                    }
                }
        }
    }
}

// ---------- launch ----------
extern "C" void kernel_launch(void* const* d_in, const int* in_sizes, int n_in,
                              void* d_out, int out_size, void* d_ws, size_t ws_size,
                              hipStream_t stream) {
    const float* x       = (const float*)d_in[0];
    const float* theta_w = (const float*)d_in[1];
    const float* theta_b = (const float*)d_in[2];
    const float* phi_w   = (const float*)d_in[3];
    const float* phi_b   = (const float*)d_in[4];
    const float* psi_w   = (const float*)d_in[5];
    const float* psi_b   = (const float*)d_in[6];
    const float* r1_w    = (const float*)d_in[7];
    const float* r1_b    = (const float*)d_in[8];
    const float* r2_w    = (const float*)d_in[9];
    const float* r2_b    = (const float*)d_in[10];
    float* out = (float*)d_out;

    constexpr int  N = 8, L = 2048, C = 512, H = 512, CH = 256;
    constexpr long NL = (long)N * L;  // 16384

    char* p = (char*)d_ws;
    auto alloc = [&](size_t bytes) { void* q = (void*)p; p += bytes; return q; };
    unsigned char*  xb8    = (unsigned char*)alloc(NL * C);            //  8 MB
    unsigned char*  TH8    = (unsigned char*)alloc(NL * H);            //  8 MB
    unsigned char*  PH8    = (unsigned char*)alloc(NL * H);            //  8 MB
    unsigned char*  VT8    = (unsigned char*)alloc((long)N * H * L);   //  8 MB
    unsigned char*  xadd8  = (unsigned char*)alloc(NL * H);            //  8 MB
    unsigned char*  h18    = (unsigned char*)alloc(NL * CH);           //  4 MB
    unsigned char*  wCat8T = (unsigned char*)alloc((long)1536 * 512);
    unsigned char*  r1T8   = (unsigned char*)alloc((long)H * CH);
    unsigned char*  r2T8   = (unsigned char*)alloc((long)CH * C);
    float*          bCat   = (float*)alloc(1536 * 4 + 256);
    unsigned short* S      = (unsigned short*)alloc((long)N * L * L * 2);  // 64 MB fp16/P-fp8

    // 1. prep
    prep<<<12294, 256, 0, stream>>>(x, theta_w, phi_w, psi_w, r1_w, r2_w,
                                    theta_b, phi_b, psi_b, xb8, wCat8T, r1T8, r2T8, bCat);

    // 2. merged fp8 projections -> TH8, PH8, VT8 (V^T via packed dword stores)
    gemm_fp8<0><<<dim3(NL / 128, 1536 / 128, 1), 256, 0, stream>>>(
        xb8, wCat8T, bCat, nullptr, nullptr, TH8, PH8, VT8, nullptr,
        C, C, C, 0, 0, 0, 0);

    // 3. S = phi @ theta^T (fp8 in, fp16 out)
    gemm_fp8<1><<<dim3(L / 128, L / 128, N), 256, 0, stream>>>(
        PH8, TH8, nullptr, nullptr, S, nullptr, nullptr, nullptr, nullptr,
        H, H, H, L, (long)L * H, (long)L * H, (long)L * L);

    // 4. softmax rows, fp16 -> fp8 in place
    softmax_fp8<<<dim3(L, N), 256, 0, stream>>>(S);

    // 5. x_add = P @ V (fp8; P rows at 4096-B pitch, V^T rows at 2048-B pitch) -> fp8
    gemm_fp8<2><<<dim3(L / 128, H / 128, N), 256, 0, stream>>>(
        (const unsigned char*)S, VT8, nullptr, nullptr, nullptr, xadd8, nullptr, nullptr, nullptr,
        L, 2 * L, L, H, (long)L * 2 * L, (long)H * L, (long)L * H);

    // 6. h1 = leaky(x_add @ r1 + b) -> fp8
    gemm_fp8<3><<<dim3(NL / 128, CH / 128, 1), 256, 0, stream>>>(
        xadd8, r1T8, r1_b, nullptr, nullptr, h18, nullptr, nullptr, nullptr,
        H, H, H, CH, 0, 0, 0);

    // 7. out = x + tanh(h1 @ r2 + b) -> fp32
    gemm_fp8<4><<<dim3(NL / 128, C / 128, 1), 256, 0, stream>>>(
        h18, r2T8, r2_b, x, nullptr, nullptr, nullptr, nullptr, out,
        CH, CH, CH, C, 0, 0, 0);
}

// Round 2
// 223.614 us; speedup vs baseline: 1.0690x; 1.0117x over previous
//
#include <hip/hip_runtime.h>
#include <hip/hip_bf16.h>

// ---------- types ----------
typedef float f32x4 __attribute__((ext_vector_type(4)));
typedef int   v8i   __attribute__((ext_vector_type(8)));
typedef __attribute__((address_space(3))) unsigned int       lds_uint;
typedef __attribute__((address_space(1))) const unsigned int glb_uint;

// ---------- helpers ----------
__device__ __forceinline__ float tanh_fast(float x) {
    float e = __expf(-2.0f * fabsf(x));
    float r = (1.0f - e) / (1.0f + e);
    return copysignf(r, x);
}
__device__ __forceinline__ unsigned char f2fp8(float v) {
    return (unsigned char)(__builtin_amdgcn_cvt_pk_fp8_f32(v, 0.0f, 0, false) & 0xff);
}
__device__ __forceinline__ unsigned short f2h(float v) {
    _Float16 h = (_Float16)v;
    unsigned short u;
    __builtin_memcpy(&u, &h, 2);
    return u;
}
__device__ __forceinline__ float h2f(unsigned short u) {
    _Float16 h;
    __builtin_memcpy(&h, &u, 2);
    return (float)h;
}

// ---------- prep: x->fp8; proj W ->fp8(x16) T; r1/r2 ->fp8(x16) T; bias concat ----------
__global__ __launch_bounds__(256) void prep(
    const float* __restrict__ x,
    const float* __restrict__ theta_w, const float* __restrict__ phi_w,
    const float* __restrict__ psi_w,   const float* __restrict__ r1_w,
    const float* __restrict__ r2_w,
    const float* __restrict__ theta_b, const float* __restrict__ phi_b,
    const float* __restrict__ psi_b,
    unsigned char* __restrict__ xb8, unsigned char* __restrict__ wCat8T,
    unsigned char* __restrict__ r1T8, unsigned char* __restrict__ r2T8,
    float* __restrict__ bCat) {
    const int b = blockIdx.x, t = threadIdx.x;
    if (b < 8192) {                       // cast x -> fp8
        long i = ((long)b * 256 + t) * 4;
        float4 f = *(const float4*)(x + i);
        int w = __builtin_amdgcn_cvt_pk_fp8_f32(f.x, f.y, 0, false);
        w = __builtin_amdgcn_cvt_pk_fp8_f32(f.z, f.w, w, true);
        *(unsigned int*)(xb8 + i) = (unsigned int)w;
    } else if (b < 11264) {               // proj weights (512x512 each), x16, transposed
        const int sel = (b - 8192) >> 10;
        const int idx = ((b - 8192) & 1023) * 256 + t;
        const float* w = sel == 0 ? theta_w : (sel == 1 ? phi_w : psi_w);
        const int r = idx >> 9, c = idx & 511;
        wCat8T[(long)(sel * 512 + c) * 512 + r] = f2fp8(w[idx] * 16.0f);
    } else if (b < 11776) {               // r1 (512x256) -> fp8 x16 T
        const int idx = (b - 11264) * 256 + t;
        const int r = idx >> 8, c = idx & 255;
        r1T8[(long)c * 512 + r] = f2fp8(r1_w[idx] * 16.0f);
    } else if (b < 12288) {               // r2 (256x512) -> fp8 x16 T
        const int idx = (b - 11776) * 256 + t;
        const int r = idx >> 9, c = idx & 511;
        r2T8[(long)c * 256 + r] = f2fp8(r2_w[idx] * 16.0f);
    } else {                              // bias concat (1536)
        const int i = (b - 12288) * 256 + t;
        if (i < 1536)
            bCat[i] = i < 512 ? theta_b[i] : (i < 1024 ? phi_b[i - 512] : psi_b[i - 1024]);
    }
}

// ---------- row softmax: read fp16 S row, write fp8 P in-place (first half of row) ----------
__global__ __launch_bounds__(256) void softmax_fp8(unsigned short* __restrict__ S) {
    const size_t row = (size_t)blockIdx.y * 2048 + blockIdx.x;
    unsigned short* p = S + row * 2048;
    const int t = threadIdx.x;
    uint4 raw = *(uint4*)(p + t * 8);
    unsigned int w[4] = {raw.x, raw.y, raw.z, raw.w};
    float v[8];
#pragma unroll
    for (int i = 0; i < 4; ++i) {
        v[2 * i]     = h2f((unsigned short)(w[i] & 0xffffu));
        v[2 * i + 1] = h2f((unsigned short)(w[i] >> 16));
    }
    float mx = v[0];
#pragma unroll
    for (int i = 1; i < 8; ++i) mx = fmaxf(mx, v[i]);
#pragma unroll
    for (int off = 32; off > 0; off >>= 1) mx = fmaxf(mx, __shfl_xor(mx, off));
    __shared__ float red[8];
    const int wave = t >> 6, lane = t & 63;
    if (lane == 0) red[wave] = mx;
    __syncthreads();
    mx = fmaxf(fmaxf(red[0], red[1]), fmaxf(red[2], red[3]));
    float s = 0.0f;
#pragma unroll
    for (int i = 0; i < 8; ++i) { v[i] = __expf(v[i] - mx); s += v[i]; }
#pragma unroll
    for (int off = 32; off > 0; off >>= 1) s += __shfl_xor(s, off);
    if (lane == 0) red[4 + wave] = s;
    __syncthreads();
    s = red[4] + red[5] + red[6] + red[7];
    const float inv = 1.0f / s;
    int o0 = __builtin_amdgcn_cvt_pk_fp8_f32(v[0] * inv, v[1] * inv, 0, false);
    o0 = __builtin_amdgcn_cvt_pk_fp8_f32(v[2] * inv, v[3] * inv, o0, true);
    int o1 = __builtin_amdgcn_cvt_pk_fp8_f32(v[4] * inv, v[5] * inv, 0, false);
    o1 = __builtin_amdgcn_cvt_pk_fp8_f32(v[6] * inv, v[7] * inv, o1, true);
    uint2 ov; ov.x = (unsigned int)o0; ov.y = (unsigned int)o1;
    *(uint2*)((unsigned char*)p + t * 8) = ov;   // after barrier 2; reads were before barrier 1
}

// ---------- fp8 GEMM: 128x128 tile, BK=128, double-buffered counted-vmcnt pipeline ----------
// C[m][n] = sum_k A[m][k]*Bt[n][k]; A/Bt fp8, row pitches ldaB/ldbB bytes.
// Pipeline (T3/T4): stage(t+1) issued BEFORE compute(t); raw s_barrier + counted
// s_waitcnt vmcnt(8) so the 8 newest global_load_lds stay in flight across the
// barrier (never vmcnt(0) mid-loop). lgkmcnt(0) before tail barrier closes the
// ds_read-vs-restage race. LDS 64KB -> 2 blocks/CU (measured occupancy was 8
// waves/CU already, so no loss).
// MODE 0 proj:  v=acc/16+bCat[col]; col<1024 -> fp8 TH8/PH8 (pitch 512);
//               col>=1024 -> V^T (dword stores: 4 l-consecutive rows packed)
// MODE 1 qkt:   fp16 -> outH, ldc elems
// MODE 2 pv:    fp8  -> out8, pitch 512
// MODE 3 r1:    v=acc/16+bias; leaky 0.2; fp8 -> out8, pitch 256
// MODE 4 r2:    v=acc/16+bias; tanh; +resid; fp32 -> outF, ldc 512
template <int MODE>
__global__ __launch_bounds__(256) void gemm_fp8(
    const unsigned char* __restrict__ A,
    const unsigned char* __restrict__ Bt,
    const float* __restrict__ bias,
    const float* __restrict__ resid,
    unsigned short* __restrict__ outH,
    unsigned char* __restrict__ out8,
    unsigned char* __restrict__ out8b,
    unsigned char* __restrict__ outV,
    float* __restrict__ outF,
    int K, int ldaB, int ldbB, int ldc, long sA, long sB, long sC) {
    __shared__ unsigned char As[2][128 * 128];
    __shared__ unsigned char Bs[2][128 * 128];

    const int tid  = threadIdx.x;
    const int lane = tid & 63, wave = tid >> 6;
    const int m16  = lane & 15, quad = lane >> 4;
    const int wm   = (wave >> 1) << 6, wn = (wave & 1) << 6;
    const int m0   = blockIdx.x << 7, n0 = blockIdx.y << 7;

    const int srow = lane >> 3;
    const int uswz = (lane & 7) ^ srow;

    const unsigned char* Abase = A  + (long)blockIdx.z * sA + (long)m0 * ldaB;
    const unsigned char* Bbase = Bt + (long)blockIdx.z * sB + (long)n0 * ldbB;
    const int stR = (wave << 5) + srow;
    const long gA0 = (long)stR * ldaB + (uswz << 4);
    const long gB0 = (long)stR * ldbB + (uswz << 4);

    // LDS read addressing: LDS 16B-unit u of row m holds global unit u^(m&7).
    // Lane's 32 global bytes (units 2q,2q+1) are contiguous at 32B region
    // P = quad ^ ((m&7)>>1); half order flips with m&1. Two ds_read_b128:
    // 8 lanes per 16B column across the wave = bank-optimal for b128.
    const int s8  = m16 & 7;                        // == m&7 == n&7 for all frags
    const int P   = quad ^ (s8 >> 1);
    const int cLo = (P << 1) + (s8 & 1);            // 16B col of global unit 2q
    const int offLo = cLo << 4;
    const int offHi = (cLo ^ 1) << 4;               // 16B col of global unit 2q+1

    f32x4 acc[4][4] = {};

    union F8 { v8i v; int4 q[2]; };

    // stage one 128-wide K-tile into buffer `buf` (8 global_load_lds / thread)
    auto STAGE = [&](int buf, int kk) {
#pragma unroll
        for (int i = 0; i < 4; ++i) {
            const unsigned char* gp = Abase + gA0 + (long)(i << 3) * ldaB + kk;
            unsigned char* lp = &As[buf][((wave << 5) + (i << 3)) << 7];
            __builtin_amdgcn_global_load_lds((glb_uint*)gp, (lds_uint*)lp, 16, 0, 0);
        }
#pragma unroll
        for (int i = 0; i < 4; ++i) {
            const unsigned char* gp = Bbase + gB0 + (long)(i << 3) * ldbB + kk;
            unsigned char* lp = &Bs[buf][((wave << 5) + (i << 3)) << 7];
            __builtin_amdgcn_global_load_lds((glb_uint*)gp, (lds_uint*)lp, 16, 0, 0);
        }
    };

    STAGE(0, 0);
    int cur = 0;
    for (int k0 = 0; k0 < K; k0 += 128) {
        if (k0 + 128 < K) {
            STAGE(cur ^ 1, k0 + 128);                       // prefetch next tile
            asm volatile("s_waitcnt vmcnt(8)" ::: "memory"); // cur tile landed; 8 newest in flight
        } else {
            asm volatile("s_waitcnt vmcnt(0)" ::: "memory"); // last tile: drain
        }
        asm volatile("s_barrier" ::: "memory");             // raw barrier: no auto vmcnt(0) drain

        const unsigned char* Ab = As[cur];
        const unsigned char* Bb = Bs[cur];
        F8 af[4], bg[4];
#pragma unroll
        for (int f = 0; f < 4; ++f) {
            const int m = wm + (f << 4) + m16;
            const int n = wn + (f << 4) + m16;
            af[f].q[0] = *(const int4*)&Ab[(m << 7) + offLo];
            af[f].q[1] = *(const int4*)&Ab[(m << 7) + offHi];
            bg[f].q[0] = *(const int4*)&Bb[(n << 7) + offLo];
            bg[f].q[1] = *(const int4*)&Bb[(n << 7) + offHi];
        }
#pragma unroll
        for (int fi = 0; fi < 4; ++fi)
#pragma unroll
            for (int fj = 0; fj < 4; ++fj)
                acc[fi][fj] = __builtin_amdgcn_mfma_scale_f32_16x16x128_f8f6f4(
                    af[fi].v, bg[fj].v, acc[fi][fj],
                    0, 0,            // cbsz=0 (A=e4m3), blgp=0 (B=e4m3)
                    0, 127,          // A scale: opsel 0, E8M0 127 = 1.0
                    0, 127);         // B scale: 1.0

        asm volatile("s_waitcnt lgkmcnt(0)" ::: "memory");  // all ds_reads of cur done
        asm volatile("s_barrier" ::: "memory");             // safe to restage into cur
        cur ^= 1;
    }

    const long zC = (long)blockIdx.z * sC;

    if (MODE == 0) {
        const int sel = n0 >> 9;                         // block-uniform
        if (sel < 2) {
            unsigned char* dst = sel == 0 ? out8 : out8b;
#pragma unroll
            for (int fj = 0; fj < 4; ++fj) {
                const int col = n0 + wn + (fj << 4) + m16;
                const int cb  = col & 511;
                const float bv = bias[col];
#pragma unroll
                for (int fi = 0; fi < 4; ++fi)
#pragma unroll
                    for (int r = 0; r < 4; ++r) {
                        const int row = m0 + wm + (fi << 4) + (quad << 2) + r;
                        dst[(long)row * 512 + cb] = f2fp8(acc[fi][fj][r] * 0.0625f + bv);
                    }
            }
        } else {                                         // V^T: pack 4 l-rows per dword
            const int z = m0 >> 11, l0 = (m0 & 2047) + wm + (quad << 2);
#pragma unroll
            for (int fj = 0; fj < 4; ++fj) {
                const int col = n0 + wn + (fj << 4) + m16;
                const int h   = col & 511;
                const float bv = bias[col];
#pragma unroll
                for (int fi = 0; fi < 4; ++fi) {
                    int w = __builtin_amdgcn_cvt_pk_fp8_f32(
                        acc[fi][fj][0] * 0.0625f + bv, acc[fi][fj][1] * 0.0625f + bv, 0, false);
                    w = __builtin_amdgcn_cvt_pk_fp8_f32(
                        acc[fi][fj][2] * 0.0625f + bv, acc[fi][fj][3] * 0.0625f + bv, w, true);
                    *(unsigned int*)(outV + ((long)z * 512 + h) * 2048 + l0 + (fi << 4)) =
                        (unsigned int)w;
                }
            }
        }
    } else {
#pragma unroll
        for (int fj = 0; fj < 4; ++fj) {
            const int col = n0 + wn + (fj << 4) + m16;
            float bv = 0.0f;
            if (MODE >= 3) bv = bias[col];
#pragma unroll
            for (int fi = 0; fi < 4; ++fi)
#pragma unroll
                for (int r = 0; r < 4; ++r) {
                    const int row = m0 + wm + (fi << 4) + (quad << 2) + r;
                    float v = acc[fi][fj][r];
                    if (MODE == 1) {
                        outH[zC + (long)row * ldc + col] = f2h(v);
                    } else if (MODE == 2) {
                        out8[zC + (long)row * 512 + col] = f2fp8(v);
                    } else if (MODE == 3) {
                        v = v * 0.0625f + bv;
                        v = v > 0.0f ? v : 0.2f * v;
                        out8[(long)row * 256 + col] = f2fp8(v);
                    } else {
                        v = v * 0.0625f + bv;
                        const long idx = (long)row * ldc + col;
                        outF[idx] = tanh_fast(v) + resid[idx];
                    }
                }
        }
    }
}

// ---------- launch ----------
extern "C" void kernel_launch(void* const* d_in, const int* in_sizes, int n_in,
                              void* d_out, int out_size, void* d_ws, size_t ws_size,
                              hipStream_t stream) {
    const float* x       = (const float*)d_in[0];
    const float* theta_w = (const float*)d_in[1];
    const float* theta_b = (const float*)d_in[2];
    const float* phi_w   = (const float*)d_in[3];
    const float* phi_b   = (const float*)d_in[4];
    const float* psi_w   = (const float*)d_in[5];
    const float* psi_b   = (const float*)d_in[6];
    const float* r1_w    = (const float*)d_in[7];
    const float* r1_b    = (const float*)d_in[8];
    const float* r2_w    = (const float*)d_in[9];
    const float* r2_b    = (const float*)d_in[10];
    float* out = (float*)d_out;

    constexpr int  N = 8, L = 2048, C = 512, H = 512, CH = 256;
    constexpr long NL = (long)N * L;  // 16384

    char* p = (char*)d_ws;
    auto alloc = [&](size_t bytes) { void* q = (void*)p; p += bytes; return q; };
    unsigned char*  xb8    = (unsigned char*)alloc(NL * C);            //  8 MB
    unsigned char*  TH8    = (unsigned char*)alloc(NL * H);            //  8 MB
    unsigned char*  PH8    = (unsigned char*)alloc(NL * H);            //  8 MB
    unsigned char*  VT8    = (unsigned char*)alloc((long)N * H * L);   //  8 MB
    unsigned char*  xadd8  = (unsigned char*)alloc(NL * H);            //  8 MB
    unsigned char*  h18    = (unsigned char*)alloc(NL * CH);           //  4 MB
    unsigned char*  wCat8T = (unsigned char*)alloc((long)1536 * 512);
    unsigned char*  r1T8   = (unsigned char*)alloc((long)H * CH);
    unsigned char*  r2T8   = (unsigned char*)alloc((long)CH * C);
    float*          bCat   = (float*)alloc(1536 * 4 + 256);
    unsigned short* S      = (unsigned short*)alloc((long)N * L * L * 2);  // 64 MB fp16/P-fp8

    // 1. prep
    prep<<<12294, 256, 0, stream>>>(x, theta_w, phi_w, psi_w, r1_w, r2_w,
                                    theta_b, phi_b, psi_b, xb8, wCat8T, r1T8, r2T8, bCat);

    // 2. merged fp8 projections -> TH8, PH8, VT8 (V^T via packed dword stores)
    gemm_fp8<0><<<dim3(NL / 128, 1536 / 128, 1), 256, 0, stream>>>(
        xb8, wCat8T, bCat, nullptr, nullptr, TH8, PH8, VT8, nullptr,
        C, C, C, 0, 0, 0, 0);

    // 3. S = phi @ theta^T (fp8 in, fp16 out)
    gemm_fp8<1><<<dim3(L / 128, L / 128, N), 256, 0, stream>>>(
        PH8, TH8, nullptr, nullptr, S, nullptr, nullptr, nullptr, nullptr,
        H, H, H, L, (long)L * H, (long)L * H, (long)L * L);

    // 4. softmax rows, fp16 -> fp8 in place
    softmax_fp8<<<dim3(L, N), 256, 0, stream>>>(S);

    // 5. x_add = P @ V (fp8; P rows at 4096-B pitch, V^T rows at 2048-B pitch) -> fp8
    gemm_fp8<2><<<dim3(L / 128, H / 128, N), 256, 0, stream>>>(
        (const unsigned char*)S, VT8, nullptr, nullptr, nullptr, xadd8, nullptr, nullptr, nullptr,
        L, 2 * L, L, H, (long)L * 2 * L, (long)H * L, (long)L * H);

    // 6. h1 = leaky(x_add @ r1 + b) -> fp8
    gemm_fp8<3><<<dim3(NL / 128, CH / 128, 1), 256, 0, stream>>>(
        xadd8, r1T8, r1_b, nullptr, nullptr, h18, nullptr, nullptr, nullptr,
        H, H, H, CH, 0, 0, 0);

    // 7. out = x + tanh(h1 @ r2 + b) -> fp32
    gemm_fp8<4><<<dim3(NL / 128, C / 128, 1), 256, 0, stream>>>(
        h18, r2T8, r2_b, x, nullptr, nullptr, nullptr, nullptr, out,
        CH, CH, CH, C, 0, 0, 0);
}